// Round 6
// baseline (27035.617 us; speedup 1.0000x reference)
//
#include <hip/hip_runtime.h>
#include <cmath>

#define Tn 4096
#define Hn 1024
#define NHn 16
#define HDn 64
#define In 4096
#define Vn 1024
#define NSTEPSn 8

enum { EPI_NONE = 0, EPI_ADD = 1, EPI_SILU = 2, EPI_MUL = 3, EPI_BIAS = 4 };

typedef __attribute__((ext_vector_type(8))) short bf16x8;
typedef __attribute__((ext_vector_type(4))) float f32x4;

__device__ inline unsigned short bf16rne(float x) {
    unsigned int u = __float_as_uint(x);
    u += 0x7fff + ((u >> 16) & 1);
    return (unsigned short)(u >> 16);
}
__device__ inline float bf2f(unsigned short h) {
    return __uint_as_float(((unsigned int)h) << 16);
}
__device__ inline void split3(float x, unsigned short& h, unsigned short& m,
                              unsigned short& l) {
    h = bf16rne(x);
    float r = x - bf2f(h);
    m = bf16rne(r);
    float r2 = r - bf2f(m);
    l = bf16rne(r2);
}

// ---------------- RoPE cos/sin table ----------------
__global__ void rope_tab_kernel(double2* __restrict__ tab) {
    int tid = threadIdx.x;  // 256 threads
    int j = tid >> 5, i = tid & 31;
    double inv = exp(-((double)(2 * i) * (1.0 / (double)HDn)) * 9.210340371976184);
    double ang = (double)j * inv;
    double2 cs;
    cs.x = cos(ang);
    cs.y = sin(ang);
    tab[tid] = cs;
}

// ---------------- Weight pre-split: W[K][N] fp32 -> W3[3][N][K] bf16 ----------------
__global__ __launch_bounds__(256) void presplit_kernel(const float* __restrict__ W,
                                                       unsigned short* __restrict__ W3,
                                                       int K, int N) {
    __shared__ float S[64][65];
    int k0 = blockIdx.y * 64, n0 = blockIdx.x * 64;
    int tid = threadIdx.x;
#pragma unroll
    for (int r = 0; r < 4; r++) {
        int idx = tid + r * 256;
        int kr = idx >> 4, c4 = (idx & 15) << 2;
        float4 v = *(const float4*)(W + (size_t)(k0 + kr) * N + n0 + c4);
        S[kr][c4] = v.x;
        S[kr][c4 + 1] = v.y;
        S[kr][c4 + 2] = v.z;
        S[kr][c4 + 3] = v.w;
    }
    __syncthreads();
    size_t PS = (size_t)N * K;
#pragma unroll
    for (int r = 0; r < 4; r++) {
        int idx = tid + r * 256;
        int kq = idx & 15, n = idx >> 4;
        ushort4 hq, mq, lq;
        split3(S[4 * kq + 0][n], hq.x, mq.x, lq.x);
        split3(S[4 * kq + 1][n], hq.y, mq.y, lq.y);
        split3(S[4 * kq + 2][n], hq.z, mq.z, lq.z);
        split3(S[4 * kq + 3][n], hq.w, mq.w, lq.w);
        size_t off = (size_t)(n0 + n) * K + k0 + 4 * kq;
        *(ushort4*)(W3 + off) = hq;
        *(ushort4*)(W3 + PS + off) = mq;
        *(ushort4*)(W3 + 2 * PS + off) = lq;
    }
}

// ---------------- RMSNorm -> bf16 triple planes (f64 math) ----------------
__global__ __launch_bounds__(256) void rmsnorm3_kernel(const float* __restrict__ x,
                                                       const float* __restrict__ w,
                                                       unsigned short* __restrict__ y3,
                                                       size_t stride) {
    int t = blockIdx.x;
    const float4* xr = (const float4*)(x + (size_t)t * Hn);
    float4 v = xr[threadIdx.x];
    double ss = (double)v.x * v.x + (double)v.y * v.y + (double)v.z * v.z + (double)v.w * v.w;
#pragma unroll
    for (int o = 1; o < 64; o <<= 1) ss += __shfl_xor(ss, o, 64);
    __shared__ double red[4];
    if ((threadIdx.x & 63) == 0) red[threadIdx.x >> 6] = ss;
    __syncthreads();
    double tot = red[0] + red[1] + red[2] + red[3];
    double rs = 1.0 / sqrt(tot * (1.0 / Hn) + 1e-6);
    const float4* wr = (const float4*)w;
    float4 wv = wr[threadIdx.x];
    float o[4];
    o[0] = (float)((double)v.x * rs * (double)wv.x);
    o[1] = (float)((double)v.y * rs * (double)wv.y);
    o[2] = (float)((double)v.z * rs * (double)wv.z);
    o[3] = (float)((double)v.w * rs * (double)wv.w);
    ushort4 hq, mq, lq;
    split3(o[0], hq.x, mq.x, lq.x);
    split3(o[1], hq.y, mq.y, lq.y);
    split3(o[2], hq.z, mq.z, lq.z);
    split3(o[3], hq.w, mq.w, lq.w);
    size_t off = (size_t)t * Hn + threadIdx.x * 4;
    *(ushort4*)(y3 + off) = hq;
    *(ushort4*)(y3 + stride + off) = mq;
    *(ushort4*)(y3 + 2 * stride + off) = lq;
}

// ---------------- Attention (f64 dot, table RoPE, f32 exp), out bf16 triple ----
__global__ __launch_bounds__(256) void attn_kernel(const float* __restrict__ q,
                                                   const float* __restrict__ K0,
                                                   const float* __restrict__ V0,
                                                   const float* __restrict__ EK,
                                                   const float* __restrict__ EV,
                                                   const int* __restrict__ toks,
                                                   const double2* __restrict__ tab,
                                                   unsigned short* __restrict__ ctx3,
                                                   size_t stride, int p) {
    int wave = blockIdx.x * 4 + (threadIdx.x >> 6);  // t*NH + head
    int lane = threadIdx.x & 63;
    int t = wave >> 4;
    int col = ((wave & 15) << 6) | lane;
    int i = lane & 31;
    int half = lane >> 5;
    size_t base = (size_t)wave * HDn + lane;

    double2 csp = tab[p * 32 + i];
    double qv = (double)q[base];
    double qpart = __shfl_xor(qv, 32, 64);
    double qr = half ? (qv * csp.x + qpart * csp.y) : (qv * csp.x - qpart * csp.y);

    double sc[NSTEPSn];
    int tk[NSTEPSn];
    double m = -1e300;
    for (int j = 0; j <= p; j++) {
        double kr;
        if (j == 0) {
            kr = (double)K0[base];
            tk[0] = 0;
        } else {
            int tok = toks[(size_t)t * NSTEPSn + (j - 1)];
            tk[j] = tok;
            double kv = (double)EK[(size_t)tok * Hn + col];
            double kpart = __shfl_xor(kv, 32, 64);
            double2 cs = tab[j * 32 + i];
            kr = half ? (kv * cs.x + kpart * cs.y) : (kv * cs.x - kpart * cs.y);
        }
        double pr = qr * kr;
#pragma unroll
        for (int o = 1; o < 64; o <<= 1) pr += __shfl_xor(pr, o, 64);
        sc[j] = pr * 0.125;
        m = fmax(m, sc[j]);
    }
    double den = 0.0;
    for (int j = 0; j <= p; j++) {
        sc[j] = (double)expf((float)(sc[j] - m));
        den += sc[j];
    }
    double invd = 1.0 / den;
    double acc = 0.0;
    for (int j = 0; j <= p; j++) {
        double vv = (j == 0) ? (double)V0[base] : (double)EV[(size_t)tk[j] * Hn + col];
        acc += sc[j] * vv;
    }
    unsigned short h, mm, l;
    split3((float)(acc * invd), h, mm, l);
    ctx3[base] = h;
    ctx3[stride + base] = mm;
    ctx3[2 * stride + base] = l;
}

// ---------------- bf16x3 MFMA GEMM, pre-split A AND B, register prefetch ------
// C(M x N) = A(M x K) @ B(K x N). A planes [3][M][K] (k-contig, stride strideA).
// B planes [3][N][K] (k-contig, row stride ldbk, plane stride strideB).
// Block: 128(M) x 64(N), 4 waves (2x2), wave = 4x2 tiles of 16x16.
// K-loop: register-prefetch chunk c+1 during MFMA of chunk c.
// Promote fp32 acc -> f64 every 2 chunks (K'=64).
template <int EPI, bool TRIPLE>
__global__ __launch_bounds__(256, 2) void gemm3_kernel(
    const unsigned short* __restrict__ A3, size_t strideA,
    const unsigned short* __restrict__ B3, size_t strideB, int ldbk,
    float* Cf, unsigned short* C3, size_t strideC,
    const float* aux, int K, int ldc) {
    __shared__ unsigned short As[3][128][40];  // [plane][m][k], +8 pad
    __shared__ unsigned short Bs[3][64][40];   // [plane][n][k], +8 pad

    int tid = threadIdx.x;
    int wv = tid >> 6, lane = tid & 63;
    int wr = wv >> 1, wc = wv & 1;
    int mblk = blockIdx.y * 128, nblk = blockIdx.x * 64;

    f32x4 acc[4][2];
    double accd[4][2][4];
#pragma unroll
    for (int mt = 0; mt < 4; mt++)
#pragma unroll
        for (int nt = 0; nt < 2; nt++) {
            acc[mt][nt] = (f32x4){0.f, 0.f, 0.f, 0.f};
#pragma unroll
            for (int r = 0; r < 4; r++) accd[mt][nt][r] = 0.0;
        }

    int rA = lane & 15;
    int kq = (lane >> 4) << 3;
    int rowA = tid >> 2, kgA = (tid & 3) << 3;  // A-stage: idx=tid (+256)
    int rowB = tid >> 2, kgB = (tid & 3) << 3;  // B-stage

    uint4 pa[6], pb[3];
    auto load_chunk = [&](int k0) {
#pragma unroll
        for (int pl = 0; pl < 3; pl++) {
            pa[pl * 2 + 0] = *(const uint4*)(A3 + (size_t)pl * strideA +
                                             (size_t)(mblk + rowA) * K + k0 + kgA);
            pa[pl * 2 + 1] = *(const uint4*)(A3 + (size_t)pl * strideA +
                                             (size_t)(mblk + rowA + 64) * K + k0 + kgA);
            pb[pl] = *(const uint4*)(B3 + (size_t)pl * strideB +
                                     (size_t)(nblk + rowB) * ldbk + k0 + kgB);
        }
    };

    int nc = K >> 5;
    load_chunk(0);
    for (int c = 0; c < nc; ++c) {
        __syncthreads();  // previous chunk's fragment reads complete
#pragma unroll
        for (int pl = 0; pl < 3; pl++) {
            *(uint4*)(&As[pl][rowA][kgA]) = pa[pl * 2 + 0];
            *(uint4*)(&As[pl][rowA + 64][kgA]) = pa[pl * 2 + 1];
            *(uint4*)(&Bs[pl][rowB][kgB]) = pb[pl];
        }
        __syncthreads();
        if (c + 1 < nc) load_chunk((c + 1) << 5);  // overlap with MFMA below

        bf16x8 Af[3][4], Bf[3][2];
#pragma unroll
        for (int pl = 0; pl < 3; pl++) {
#pragma unroll
            for (int mt = 0; mt < 4; mt++)
                Af[pl][mt] = *(const bf16x8*)(&As[pl][wr * 64 + mt * 16 + rA][kq]);
#pragma unroll
            for (int nt = 0; nt < 2; nt++)
                Bf[pl][nt] = *(const bf16x8*)(&Bs[pl][wc * 32 + nt * 16 + rA][kq]);
        }
#pragma unroll
        for (int mt = 0; mt < 4; mt++)
#pragma unroll
            for (int nt = 0; nt < 2; nt++) {
                f32x4 a = acc[mt][nt];
                a = __builtin_amdgcn_mfma_f32_16x16x32_bf16(Af[0][mt], Bf[0][nt], a, 0, 0, 0);
                a = __builtin_amdgcn_mfma_f32_16x16x32_bf16(Af[0][mt], Bf[1][nt], a, 0, 0, 0);
                a = __builtin_amdgcn_mfma_f32_16x16x32_bf16(Af[1][mt], Bf[0][nt], a, 0, 0, 0);
                a = __builtin_amdgcn_mfma_f32_16x16x32_bf16(Af[1][mt], Bf[1][nt], a, 0, 0, 0);
                a = __builtin_amdgcn_mfma_f32_16x16x32_bf16(Af[0][mt], Bf[2][nt], a, 0, 0, 0);
                a = __builtin_amdgcn_mfma_f32_16x16x32_bf16(Af[2][mt], Bf[0][nt], a, 0, 0, 0);
                acc[mt][nt] = a;
            }

        if (c & 1) {  // promote fp32 -> f64 every 2 chunks (K'=64)
#pragma unroll
            for (int mt = 0; mt < 4; mt++)
#pragma unroll
                for (int nt = 0; nt < 2; nt++)
#pragma unroll
                    for (int r = 0; r < 4; r++) {
                        accd[mt][nt][r] += (double)acc[mt][nt][r];
                        acc[mt][nt][r] = 0.f;
                    }
        }
    }

    // ---- epilogue (f64), write f32 or bf16-triple ----
#pragma unroll
    for (int mt = 0; mt < 4; mt++)
#pragma unroll
        for (int nt = 0; nt < 2; nt++) {
            int n = nblk + wc * 32 + nt * 16 + (lane & 15);
            int mb = mblk + wr * 64 + mt * 16 + ((lane >> 4) << 2);
#pragma unroll
            for (int r = 0; r < 4; r++) {
                int m = mb + r;
                size_t off = (size_t)m * ldc + n;
                double v = accd[mt][nt][r];
                if (EPI == EPI_ADD) v += (double)aux[off];
                if (EPI == EPI_SILU) {
                    float vf = (float)v;
                    v = (double)(vf / (1.0f + expf(-vf)));
                }
                if (EPI == EPI_MUL) v *= (double)aux[off];
                if (EPI == EPI_BIAS) v += (double)aux[n];
                if (TRIPLE) {
                    unsigned short h, mm, l;
                    split3((float)v, h, mm, l);
                    C3[off] = h;
                    C3[strideC + off] = mm;
                    C3[2 * strideC + off] = l;
                } else {
                    Cf[off] = (float)v;
                }
            }
        }
}

// ---------------- Argmax over f32 logits (first-max tie-break) ----------------
__global__ __launch_bounds__(256) void argmax_kernel(const float* __restrict__ logits,
                                                     int* __restrict__ out_tok, int p) {
    int t = blockIdx.x;
    const float* lr = logits + (size_t)t * Vn;
    float bv = -INFINITY;
    int bi = 0x7fffffff;
    for (int j = threadIdx.x; j < Vn; j += 256) {
        float v = lr[j];
        if (v > bv || (v == bv && j < bi)) {
            bv = v;
            bi = j;
        }
    }
#pragma unroll
    for (int o = 1; o < 64; o <<= 1) {
        float ov = __shfl_xor(bv, o, 64);
        int oi = __shfl_xor(bi, o, 64);
        if (ov > bv || (ov == bv && oi < bi)) {
            bv = ov;
            bi = oi;
        }
    }
    __shared__ float sv[4];
    __shared__ int si[4];
    if ((threadIdx.x & 63) == 0) {
        sv[threadIdx.x >> 6] = bv;
        si[threadIdx.x >> 6] = bi;
    }
    __syncthreads();
    if (threadIdx.x == 0) {
        for (int w = 1; w < 4; w++) {
            if (sv[w] > bv || (sv[w] == bv && si[w] < bi)) {
                bv = sv[w];
                bi = si[w];
            }
        }
        out_tok[(size_t)t * NSTEPSn + p] = bi;
    }
}

// ---------------- Embedding gather ----------------
__global__ __launch_bounds__(256) void embed_kernel(const float* __restrict__ E,
                                                    const int* __restrict__ toks,
                                                    float* __restrict__ x, int p) {
    int t = blockIdx.x;
    int tok = toks[(size_t)t * NSTEPSn + p];
    float4 v = ((const float4*)(E + (size_t)tok * Hn))[threadIdx.x];
    ((float4*)(x + (size_t)t * Hn))[threadIdx.x] = v;
}

extern "C" void kernel_launch(void* const* d_in, const int* in_sizes, int n_in,
                              void* d_out, int out_size, void* d_ws, size_t ws_size,
                              hipStream_t stream) {
    const float* x0 = (const float*)d_in[0];
    const float* Wq = (const float*)d_in[1];
    const float* Wk = (const float*)d_in[2];
    const float* Wv = (const float*)d_in[3];
    const float* Wo = (const float*)d_in[4];
    const float* Wg = (const float*)d_in[5];
    const float* Wu = (const float*)d_in[6];
    const float* Wd = (const float*)d_in[7];
    const float* n1 = (const float*)d_in[8];
    const float* n2 = (const float*)d_in[9];
    const float* Emb = (const float*)d_in[10];
    const float* Wout = (const float*)d_in[11];
    const float* bout = (const float*)d_in[12];
    int* toks = (int*)d_out;

    float* ws = (float*)d_ws;
    const size_t M1 = 1024 * 1024;
    float* EK = ws;                  // V x H fp32           4MB
    float* EV = ws + 1 * M1;         //                      4MB
    float* K0 = ws + 2 * M1;         // T x H fp32           16MB
    float* V0 = ws + 6 * M1;         //                      16MB
    float* xb = ws + 10 * M1;        // residual hidden      16MB
    float* qb = ws + 14 * M1;        // q / MLP acc / logits 16MB
    float* Gc = ws + 18 * M1;        // silu chunk fp32      16MB
    unsigned short* s3a = (unsigned short*)(ws + 22 * M1);  // triple TxH  24MB
    unsigned short* s3g = (unsigned short*)(ws + 28 * M1);  // triple TxH  24MB
    double2* tab = (double2*)(ws + 34 * M1);                // 256 double2  4KB
    unsigned short* W3q = (unsigned short*)(ws + 34 * M1 + 1024);  // 6MB
    unsigned short* W3k = W3q + 3 * M1;                            // 6MB
    unsigned short* W3v = W3k + 3 * M1;                            // 6MB
    unsigned short* W3o = W3v + 3 * M1;                            // 6MB
    unsigned short* W3t = W3o + 3 * M1;  // Wout               6MB
    unsigned short* W3g = W3t + 3 * M1;                            // 24MB
    unsigned short* W3u = W3g + 12 * M1;                           // 24MB
    unsigned short* W3d = W3u + 12 * M1;                           // 24MB
    // total = 34M + 1K + 7.5M + 18M floats ~= 238 MB

    const size_t STH = (size_t)Tn * Hn;  // plane stride, T x 1024 triples
    const size_t SVH = (size_t)Vn * Hn;  // plane stride, V x H triple
    const size_t SW1 = M1;               // plane stride, 1M-element weights
    const size_t SW4 = 4 * M1;           // plane stride, 4M-element weights

    dim3 blk(256);
    dim3 gTH(Hn / 64, Tn / 128);  // (16, 32): M=T, N=1024
    dim3 gVH(Hn / 64, Vn / 128);  // (16, 8):  M=V, N=1024

    // ---- One-time precompute ----
    rope_tab_kernel<<<1, 256, 0, stream>>>(tab);
    presplit_kernel<<<dim3(16, 16), blk, 0, stream>>>(Wq, W3q, Hn, Hn);
    presplit_kernel<<<dim3(16, 16), blk, 0, stream>>>(Wk, W3k, Hn, Hn);
    presplit_kernel<<<dim3(16, 16), blk, 0, stream>>>(Wv, W3v, Hn, Hn);
    presplit_kernel<<<dim3(16, 16), blk, 0, stream>>>(Wo, W3o, Hn, Hn);
    presplit_kernel<<<dim3(16, 16), blk, 0, stream>>>(Wout, W3t, Hn, Vn);
    presplit_kernel<<<dim3(In / 64, Hn / 64), blk, 0, stream>>>(Wg, W3g, Hn, In);
    presplit_kernel<<<dim3(In / 64, Hn / 64), blk, 0, stream>>>(Wu, W3u, Hn, In);
    presplit_kernel<<<dim3(Hn / 64, In / 64), blk, 0, stream>>>(Wd, W3d, In, Hn);
    rmsnorm3_kernel<<<Vn, 256, 0, stream>>>(Emb, n1, s3a, SVH);
    gemm3_kernel<EPI_NONE, false><<<gVH, blk, 0, stream>>>(
        s3a, SVH, W3k, SW1, Hn, EK, nullptr, 0, nullptr, Hn, Hn);
    gemm3_kernel<EPI_NONE, false><<<gVH, blk, 0, stream>>>(
        s3a, SVH, W3v, SW1, Hn, EV, nullptr, 0, nullptr, Hn, Hn);

    for (int p = 0; p < NSTEPSn; p++) {
        const float* src = (p == 0) ? x0 : xb;

        rmsnorm3_kernel<<<Tn, 256, 0, stream>>>(src, n1, s3a, STH);
        gemm3_kernel<EPI_NONE, false><<<gTH, blk, 0, stream>>>(
            s3a, STH, W3q, SW1, Hn, qb, nullptr, 0, nullptr, Hn, Hn);
        if (p == 0) {
            gemm3_kernel<EPI_NONE, false><<<gTH, blk, 0, stream>>>(
                s3a, STH, W3k, SW1, Hn, K0, nullptr, 0, nullptr, Hn, Hn);
            gemm3_kernel<EPI_NONE, false><<<gTH, blk, 0, stream>>>(
                s3a, STH, W3v, SW1, Hn, V0, nullptr, 0, nullptr, Hn, Hn);
        }
        attn_kernel<<<(Tn * NHn) / 4, 256, 0, stream>>>(qb, K0, V0, EK, EV, toks,
                                                        tab, s3a, STH, p);
        // h2 = ctx @ Wo + src  (in-place into xb when src == xb)
        gemm3_kernel<EPI_ADD, false><<<gTH, blk, 0, stream>>>(
            s3a, STH, W3o, SW1, Hn, xb, nullptr, 0, src, Hn, Hn);
        rmsnorm3_kernel<<<Tn, 256, 0, stream>>>(xb, n2, s3a, STH);
        // Gated MLP, chunked over I (4 x 1024), pre-split weights; acc into qb.
        for (int c = 0; c < 4; c++) {
            gemm3_kernel<EPI_SILU, false><<<gTH, blk, 0, stream>>>(
                s3a, STH, W3g + (size_t)c * M1, SW4, Hn,
                Gc, nullptr, 0, nullptr, Hn, 1024);
            gemm3_kernel<EPI_MUL, true><<<gTH, blk, 0, stream>>>(
                s3a, STH, W3u + (size_t)c * M1, SW4, Hn,
                nullptr, s3g, STH, Gc, Hn, 1024);
            if (c < 3) {
                gemm3_kernel<EPI_ADD, false><<<gTH, blk, 0, stream>>>(
                    s3g, STH, W3d + (size_t)c * 1024, SW4, In,
                    qb, nullptr, 0, (c == 0) ? xb : qb, Hn, Hn);
            } else {
                gemm3_kernel<EPI_ADD, true><<<gTH, blk, 0, stream>>>(
                    s3g, STH, W3d + (size_t)c * 1024, SW4, In,
                    nullptr, s3a, STH, qb, Hn, Hn);
            }
        }
        // logits = out @ Wout + bout  (into qb)
        gemm3_kernel<EPI_BIAS, false><<<gTH, blk, 0, stream>>>(
            s3a, STH, W3t, SW1, Hn, qb, nullptr, 0, bout, Hn, Vn);
        argmax_kernel<<<Tn, 256, 0, stream>>>(qb, toks, p);
        if (p < NSTEPSn - 1) embed_kernel<<<Tn, 256, 0, stream>>>(Emb, toks, xb, p);
    }
}

// Round 7
// 7774.456 us; speedup vs baseline: 3.4775x; 3.4775x over previous
//
#include <hip/hip_runtime.h>
#include <cmath>

#define Tn 4096
#define Hn 1024
#define NHn 16
#define HDn 64
#define In 4096
#define Vn 1024
#define NSTEPSn 8

enum { EPI_NONE = 0, EPI_ADD = 1, EPI_SILU = 2, EPI_MUL = 3, EPI_BIAS = 4 };

typedef __attribute__((ext_vector_type(8))) short bf16x8;
typedef __attribute__((ext_vector_type(4))) float f32x4;

__device__ inline unsigned short bf16rne(float x) {
    unsigned int u = __float_as_uint(x);
    u += 0x7fff + ((u >> 16) & 1);
    return (unsigned short)(u >> 16);
}
__device__ inline float bf2f(unsigned short h) {
    return __uint_as_float(((unsigned int)h) << 16);
}
__device__ inline void split3(float x, unsigned short& h, unsigned short& m,
                              unsigned short& l) {
    h = bf16rne(x);
    float r = x - bf2f(h);
    m = bf16rne(r);
    float r2 = r - bf2f(m);
    l = bf16rne(r2);
}

// Async global->LDS, 16B per lane. LDS dest must be wave-uniform base; HW
// writes base + lane*16. Pointers converted via uintptr (low 32 bits = LDS
// offset for AS3; flat address for AS1).
__device__ __forceinline__ void gload_lds(const unsigned short* g,
                                          const unsigned short* l) {
    __builtin_amdgcn_global_load_lds(
        (const __attribute__((address_space(1))) unsigned int*)(uintptr_t)g,
        (__attribute__((address_space(3))) unsigned int*)(unsigned int)(uintptr_t)l,
        16, 0, 0);
}

// ---------------- RoPE cos/sin table ----------------
__global__ void rope_tab_kernel(double2* __restrict__ tab) {
    int tid = threadIdx.x;  // 256 threads
    int j = tid >> 5, i = tid & 31;
    double inv = exp(-((double)(2 * i) * (1.0 / (double)HDn)) * 9.210340371976184);
    double ang = (double)j * inv;
    double2 cs;
    cs.x = cos(ang);
    cs.y = sin(ang);
    tab[tid] = cs;
}

// ---------------- Weight pre-split: W[K][N] fp32 -> W3[3][N][K] bf16 ----------------
__global__ __launch_bounds__(256) void presplit_kernel(const float* __restrict__ W,
                                                       unsigned short* __restrict__ W3,
                                                       int K, int N) {
    __shared__ float S[64][65];
    int k0 = blockIdx.y * 64, n0 = blockIdx.x * 64;
    int tid = threadIdx.x;
#pragma unroll
    for (int r = 0; r < 4; r++) {
        int idx = tid + r * 256;
        int kr = idx >> 4, c4 = (idx & 15) << 2;
        float4 v = *(const float4*)(W + (size_t)(k0 + kr) * N + n0 + c4);
        S[kr][c4] = v.x;
        S[kr][c4 + 1] = v.y;
        S[kr][c4 + 2] = v.z;
        S[kr][c4 + 3] = v.w;
    }
    __syncthreads();
    size_t PS = (size_t)N * K;
#pragma unroll
    for (int r = 0; r < 4; r++) {
        int idx = tid + r * 256;
        int kq = idx & 15, n = idx >> 4;
        ushort4 hq, mq, lq;
        split3(S[4 * kq + 0][n], hq.x, mq.x, lq.x);
        split3(S[4 * kq + 1][n], hq.y, mq.y, lq.y);
        split3(S[4 * kq + 2][n], hq.z, mq.z, lq.z);
        split3(S[4 * kq + 3][n], hq.w, mq.w, lq.w);
        size_t off = (size_t)(n0 + n) * K + k0 + 4 * kq;
        *(ushort4*)(W3 + off) = hq;
        *(ushort4*)(W3 + PS + off) = mq;
        *(ushort4*)(W3 + 2 * PS + off) = lq;
    }
}

// ---------------- RMSNorm -> bf16 triple planes (f64 math) ----------------
__global__ __launch_bounds__(256) void rmsnorm3_kernel(const float* __restrict__ x,
                                                       const float* __restrict__ w,
                                                       unsigned short* __restrict__ y3,
                                                       size_t stride) {
    int t = blockIdx.x;
    const float4* xr = (const float4*)(x + (size_t)t * Hn);
    float4 v = xr[threadIdx.x];
    double ss = (double)v.x * v.x + (double)v.y * v.y + (double)v.z * v.z + (double)v.w * v.w;
#pragma unroll
    for (int o = 1; o < 64; o <<= 1) ss += __shfl_xor(ss, o, 64);
    __shared__ double red[4];
    if ((threadIdx.x & 63) == 0) red[threadIdx.x >> 6] = ss;
    __syncthreads();
    double tot = red[0] + red[1] + red[2] + red[3];
    double rs = 1.0 / sqrt(tot * (1.0 / Hn) + 1e-6);
    const float4* wr = (const float4*)w;
    float4 wv = wr[threadIdx.x];
    float o[4];
    o[0] = (float)((double)v.x * rs * (double)wv.x);
    o[1] = (float)((double)v.y * rs * (double)wv.y);
    o[2] = (float)((double)v.z * rs * (double)wv.z);
    o[3] = (float)((double)v.w * rs * (double)wv.w);
    ushort4 hq, mq, lq;
    split3(o[0], hq.x, mq.x, lq.x);
    split3(o[1], hq.y, mq.y, lq.y);
    split3(o[2], hq.z, mq.z, lq.z);
    split3(o[3], hq.w, mq.w, lq.w);
    size_t off = (size_t)t * Hn + threadIdx.x * 4;
    *(ushort4*)(y3 + off) = hq;
    *(ushort4*)(y3 + stride + off) = mq;
    *(ushort4*)(y3 + 2 * stride + off) = lq;
}

// ---------------- Attention (f64 dot, table RoPE, f32 exp), out bf16 triple ----
__global__ __launch_bounds__(256) void attn_kernel(const float* __restrict__ q,
                                                   const float* __restrict__ K0,
                                                   const float* __restrict__ V0,
                                                   const float* __restrict__ EK,
                                                   const float* __restrict__ EV,
                                                   const int* __restrict__ toks,
                                                   const double2* __restrict__ tab,
                                                   unsigned short* __restrict__ ctx3,
                                                   size_t stride, int p) {
    int wave = blockIdx.x * 4 + (threadIdx.x >> 6);  // t*NH + head
    int lane = threadIdx.x & 63;
    int t = wave >> 4;
    int col = ((wave & 15) << 6) | lane;
    int i = lane & 31;
    int half = lane >> 5;
    size_t base = (size_t)wave * HDn + lane;

    double2 csp = tab[p * 32 + i];
    double qv = (double)q[base];
    double qpart = __shfl_xor(qv, 32, 64);
    double qr = half ? (qv * csp.x + qpart * csp.y) : (qv * csp.x - qpart * csp.y);

    double sc[NSTEPSn];
    int tk[NSTEPSn];
    double m = -1e300;
    for (int j = 0; j <= p; j++) {
        double kr;
        if (j == 0) {
            kr = (double)K0[base];
            tk[0] = 0;
        } else {
            int tok = toks[(size_t)t * NSTEPSn + (j - 1)];
            tk[j] = tok;
            double kv = (double)EK[(size_t)tok * Hn + col];
            double kpart = __shfl_xor(kv, 32, 64);
            double2 cs = tab[j * 32 + i];
            kr = half ? (kv * cs.x + kpart * cs.y) : (kv * cs.x - kpart * cs.y);
        }
        double pr = qr * kr;
#pragma unroll
        for (int o = 1; o < 64; o <<= 1) pr += __shfl_xor(pr, o, 64);
        sc[j] = pr * 0.125;
        m = fmax(m, sc[j]);
    }
    double den = 0.0;
    for (int j = 0; j <= p; j++) {
        sc[j] = (double)expf((float)(sc[j] - m));
        den += sc[j];
    }
    double invd = 1.0 / den;
    double acc = 0.0;
    for (int j = 0; j <= p; j++) {
        double vv = (j == 0) ? (double)V0[base] : (double)EV[(size_t)tk[j] * Hn + col];
        acc += sc[j] * vv;
    }
    unsigned short h, mm, l;
    split3((float)(acc * invd), h, mm, l);
    ctx3[base] = h;
    ctx3[stride + base] = mm;
    ctx3[2 * stride + base] = l;
}

// ---------------- bf16x3 MFMA GEMM, async LDS double-buffer ----------------
// C(M x N) = A(M x K) @ B(K x N). A planes [3][M][K] (k-contig), B planes
// [3][N][K] (k-contig, row stride ldbk). Block 128(M) x 64(N), 4 waves (2x2),
// wave tile 64x32 (4x2 of 16x16). Staging: global_load_lds width-16 into
// pad-free LDS [3][rows][32], double-buffered; one barrier per chunk.
// Promote fp32 acc -> f64 every 2 chunks (K'=64).
#define ABUF 12288  // 3*128*32 ushorts
#define BBUF 6144   // 3*64*32 ushorts
template <int EPI, bool TRIPLE>
__global__ __launch_bounds__(256, 2) void gemm3_kernel(
    const unsigned short* __restrict__ A3, size_t strideA,
    const unsigned short* __restrict__ B3, size_t strideB, int ldbk,
    float* Cf, unsigned short* C3, size_t strideC,
    const float* aux, int K, int ldc) {
    __shared__ unsigned short lds[2][ABUF + BBUF];  // 72 KB

    int tid = threadIdx.x;
    int wv = tid >> 6, lane = tid & 63;
    int wr = wv >> 1, wc = wv & 1;
    int mblk = blockIdx.y * 128, nblk = blockIdx.x * 64;

    // ---- per-wave staging segments: 9 x 1KB (A: 24 segs, B: 12 segs) ----
    int lrow = lane >> 2, lcol = (lane & 3) << 3;
    const unsigned short* gseg0;
    const unsigned short* gseg1;
    const unsigned short* gseg2;
    const unsigned short* gseg3;
    const unsigned short* gseg4;
    const unsigned short* gseg5;
    const unsigned short* gseg6;
    const unsigned short* gseg7;
    const unsigned short* gseg8;
    unsigned lseg0, lseg1, lseg2, lseg3, lseg4, lseg5, lseg6, lseg7, lseg8;
#define SEGINIT(IDX)                                                              \
    {                                                                             \
        int s = wv * 9 + IDX;                                                     \
        if (s < 24) {                                                             \
            int pl = s >> 3, sub = s & 7;                                         \
            gseg##IDX = A3 + (size_t)pl * strideA +                               \
                        (size_t)(mblk + sub * 16 + lrow) * K + lcol;              \
            lseg##IDX = pl * 4096 + sub * 512;                                    \
        } else {                                                                  \
            int u = s - 24;                                                       \
            int pl = u >> 2, sub = u & 3;                                         \
            gseg##IDX = B3 + (size_t)pl * strideB +                               \
                        (size_t)(nblk + sub * 16 + lrow) * ldbk + lcol;           \
            lseg##IDX = ABUF + pl * 2048 + sub * 512;                             \
        }                                                                         \
    }
    SEGINIT(0) SEGINIT(1) SEGINIT(2) SEGINIT(3) SEGINIT(4)
    SEGINIT(5) SEGINIT(6) SEGINIT(7) SEGINIT(8)
#undef SEGINIT

#define ISSUE(BUF, KOFF)                                                          \
    {                                                                             \
        unsigned short* lb = &lds[BUF][0];                                        \
        gload_lds(gseg0 + (KOFF), lb + lseg0);                                    \
        gload_lds(gseg1 + (KOFF), lb + lseg1);                                    \
        gload_lds(gseg2 + (KOFF), lb + lseg2);                                    \
        gload_lds(gseg3 + (KOFF), lb + lseg3);                                    \
        gload_lds(gseg4 + (KOFF), lb + lseg4);                                    \
        gload_lds(gseg5 + (KOFF), lb + lseg5);                                    \
        gload_lds(gseg6 + (KOFF), lb + lseg6);                                    \
        gload_lds(gseg7 + (KOFF), lb + lseg7);                                    \
        gload_lds(gseg8 + (KOFF), lb + lseg8);                                    \
    }

    f32x4 acc[4][2];
    double accd[4][2][4];
#pragma unroll
    for (int mt = 0; mt < 4; mt++)
#pragma unroll
        for (int nt = 0; nt < 2; nt++) {
            acc[mt][nt] = (f32x4){0.f, 0.f, 0.f, 0.f};
#pragma unroll
            for (int r = 0; r < 4; r++) accd[mt][nt][r] = 0.0;
        }

    int rA = lane & 15;
    int kq = (lane >> 4) << 3;

    int nc = K >> 5;
    ISSUE(0, 0)
    __syncthreads();
    for (int c = 0; c < nc; ++c) {
        int cur = c & 1;
        if (c + 1 < nc) ISSUE(cur ^ 1, (c + 1) << 5)

        const unsigned short* base = &lds[cur][0];
        bf16x8 Af[3][4], Bf[3][2];
#pragma unroll
        for (int pl = 0; pl < 3; pl++) {
#pragma unroll
            for (int mt = 0; mt < 4; mt++)
                Af[pl][mt] = *(const bf16x8*)(base + pl * 4096 +
                                              (wr * 64 + mt * 16 + rA) * 32 + kq);
#pragma unroll
            for (int nt = 0; nt < 2; nt++)
                Bf[pl][nt] = *(const bf16x8*)(base + ABUF + pl * 2048 +
                                              (wc * 32 + nt * 16 + rA) * 32 + kq);
        }
#pragma unroll
        for (int mt = 0; mt < 4; mt++)
#pragma unroll
            for (int nt = 0; nt < 2; nt++) {
                f32x4 a = acc[mt][nt];
                a = __builtin_amdgcn_mfma_f32_16x16x32_bf16(Af[0][mt], Bf[0][nt], a, 0, 0, 0);
                a = __builtin_amdgcn_mfma_f32_16x16x32_bf16(Af[0][mt], Bf[1][nt], a, 0, 0, 0);
                a = __builtin_amdgcn_mfma_f32_16x16x32_bf16(Af[1][mt], Bf[0][nt], a, 0, 0, 0);
                a = __builtin_amdgcn_mfma_f32_16x16x32_bf16(Af[1][mt], Bf[1][nt], a, 0, 0, 0);
                a = __builtin_amdgcn_mfma_f32_16x16x32_bf16(Af[0][mt], Bf[2][nt], a, 0, 0, 0);
                a = __builtin_amdgcn_mfma_f32_16x16x32_bf16(Af[2][mt], Bf[0][nt], a, 0, 0, 0);
                acc[mt][nt] = a;
            }

        if (c & 1) {  // promote fp32 -> f64 every 2 chunks (K'=64)
#pragma unroll
            for (int mt = 0; mt < 4; mt++)
#pragma unroll
                for (int nt = 0; nt < 2; nt++)
#pragma unroll
                    for (int r = 0; r < 4; r++) {
                        accd[mt][nt][r] += (double)acc[mt][nt][r];
                        acc[mt][nt][r] = 0.f;
                    }
        }
        __syncthreads();  // drains prefetch (post-MFMA) + guards buffer reuse
    }
#undef ISSUE

    // ---- epilogue (f64), write f32 or bf16-triple ----
#pragma unroll
    for (int mt = 0; mt < 4; mt++)
#pragma unroll
        for (int nt = 0; nt < 2; nt++) {
            int n = nblk + wc * 32 + nt * 16 + (lane & 15);
            int mb = mblk + wr * 64 + mt * 16 + ((lane >> 4) << 2);
#pragma unroll
            for (int r = 0; r < 4; r++) {
                int m = mb + r;
                size_t off = (size_t)m * ldc + n;
                double v = accd[mt][nt][r];
                if (EPI == EPI_ADD) v += (double)aux[off];
                if (EPI == EPI_SILU) {
                    float vf = (float)v;
                    v = (double)(vf / (1.0f + expf(-vf)));
                }
                if (EPI == EPI_MUL) v *= (double)aux[off];
                if (EPI == EPI_BIAS) v += (double)aux[n];
                if (TRIPLE) {
                    unsigned short h, mm, l;
                    split3((float)v, h, mm, l);
                    C3[off] = h;
                    C3[strideC + off] = mm;
                    C3[2 * strideC + off] = l;
                } else {
                    Cf[off] = (float)v;
                }
            }
        }
}

// ---------------- Argmax over f32 logits (first-max tie-break) ----------------
__global__ __launch_bounds__(256) void argmax_kernel(const float* __restrict__ logits,
                                                     int* __restrict__ out_tok, int p) {
    int t = blockIdx.x;
    const float* lr = logits + (size_t)t * Vn;
    float bv = -INFINITY;
    int bi = 0x7fffffff;
    for (int j = threadIdx.x; j < Vn; j += 256) {
        float v = lr[j];
        if (v > bv || (v == bv && j < bi)) {
            bv = v;
            bi = j;
        }
    }
#pragma unroll
    for (int o = 1; o < 64; o <<= 1) {
        float ov = __shfl_xor(bv, o, 64);
        int oi = __shfl_xor(bi, o, 64);
        if (ov > bv || (ov == bv && oi < bi)) {
            bv = ov;
            bi = oi;
        }
    }
    __shared__ float sv[4];
    __shared__ int si[4];
    if ((threadIdx.x & 63) == 0) {
        sv[threadIdx.x >> 6] = bv;
        si[threadIdx.x >> 6] = bi;
    }
    __syncthreads();
    if (threadIdx.x == 0) {
        for (int w = 1; w < 4; w++) {
            if (sv[w] > bv || (sv[w] == bv && si[w] < bi)) {
                bv = sv[w];
                bi = si[w];
            }
        }
        out_tok[(size_t)t * NSTEPSn + p] = bi;
    }
}

// ---------------- Embedding gather ----------------
__global__ __launch_bounds__(256) void embed_kernel(const float* __restrict__ E,
                                                    const int* __restrict__ toks,
                                                    float* __restrict__ x, int p) {
    int t = blockIdx.x;
    int tok = toks[(size_t)t * NSTEPSn + p];
    float4 v = ((const float4*)(E + (size_t)tok * Hn))[threadIdx.x];
    ((float4*)(x + (size_t)t * Hn))[threadIdx.x] = v;
}

extern "C" void kernel_launch(void* const* d_in, const int* in_sizes, int n_in,
                              void* d_out, int out_size, void* d_ws, size_t ws_size,
                              hipStream_t stream) {
    const float* x0 = (const float*)d_in[0];
    const float* Wq = (const float*)d_in[1];
    const float* Wk = (const float*)d_in[2];
    const float* Wv = (const float*)d_in[3];
    const float* Wo = (const float*)d_in[4];
    const float* Wg = (const float*)d_in[5];
    const float* Wu = (const float*)d_in[6];
    const float* Wd = (const float*)d_in[7];
    const float* n1 = (const float*)d_in[8];
    const float* n2 = (const float*)d_in[9];
    const float* Emb = (const float*)d_in[10];
    const float* Wout = (const float*)d_in[11];
    const float* bout = (const float*)d_in[12];
    int* toks = (int*)d_out;

    float* ws = (float*)d_ws;
    const size_t M1 = 1024 * 1024;
    float* EK = ws;                  // V x H fp32           4MB
    float* EV = ws + 1 * M1;         //                      4MB
    float* K0 = ws + 2 * M1;         // T x H fp32           16MB
    float* V0 = ws + 6 * M1;         //                      16MB
    float* xb = ws + 10 * M1;        // residual hidden      16MB
    float* qb = ws + 14 * M1;        // q / MLP acc / logits 16MB
    float* Gc = ws + 18 * M1;        // silu chunk fp32      16MB
    unsigned short* s3a = (unsigned short*)(ws + 22 * M1);  // triple TxH  24MB
    unsigned short* s3g = (unsigned short*)(ws + 28 * M1);  // triple TxH  24MB
    double2* tab = (double2*)(ws + 34 * M1);                // 256 double2  4KB
    unsigned short* W3q = (unsigned short*)(ws + 34 * M1 + 1024);  // 6MB
    unsigned short* W3k = W3q + 3 * M1;                            // 6MB
    unsigned short* W3v = W3k + 3 * M1;                            // 6MB
    unsigned short* W3o = W3v + 3 * M1;                            // 6MB
    unsigned short* W3t = W3o + 3 * M1;  // Wout                     6MB
    unsigned short* W3g = W3t + 3 * M1;                            // 24MB
    unsigned short* W3u = W3g + 12 * M1;                           // 24MB
    unsigned short* W3d = W3u + 12 * M1;                           // 24MB
    // total ~= 238 MB

    const size_t STH = (size_t)Tn * Hn;  // plane stride, T x 1024 triples
    const size_t SVH = (size_t)Vn * Hn;  // plane stride, V x H triple
    const size_t SW1 = M1;               // plane stride, 1M-element weights
    const size_t SW4 = 4 * M1;           // plane stride, 4M-element weights

    dim3 blk(256);
    dim3 gTH(Hn / 64, Tn / 128);  // (16, 32): M=T, N=1024
    dim3 gVH(Hn / 64, Vn / 128);  // (16, 8):  M=V, N=1024

    // ---- One-time precompute ----
    rope_tab_kernel<<<1, 256, 0, stream>>>(tab);
    presplit_kernel<<<dim3(16, 16), blk, 0, stream>>>(Wq, W3q, Hn, Hn);
    presplit_kernel<<<dim3(16, 16), blk, 0, stream>>>(Wk, W3k, Hn, Hn);
    presplit_kernel<<<dim3(16, 16), blk, 0, stream>>>(Wv, W3v, Hn, Hn);
    presplit_kernel<<<dim3(16, 16), blk, 0, stream>>>(Wo, W3o, Hn, Hn);
    presplit_kernel<<<dim3(16, 16), blk, 0, stream>>>(Wout, W3t, Hn, Vn);
    presplit_kernel<<<dim3(In / 64, Hn / 64), blk, 0, stream>>>(Wg, W3g, Hn, In);
    presplit_kernel<<<dim3(In / 64, Hn / 64), blk, 0, stream>>>(Wu, W3u, Hn, In);
    presplit_kernel<<<dim3(Hn / 64, In / 64), blk, 0, stream>>>(Wd, W3d, In, Hn);
    rmsnorm3_kernel<<<Vn, 256, 0, stream>>>(Emb, n1, s3a, SVH);
    gemm3_kernel<EPI_NONE, false><<<gVH, blk, 0, stream>>>(
        s3a, SVH, W3k, SW1, Hn, EK, nullptr, 0, nullptr, Hn, Hn);
    gemm3_kernel<EPI_NONE, false><<<gVH, blk, 0, stream>>>(
        s3a, SVH, W3v, SW1, Hn, EV, nullptr, 0, nullptr, Hn, Hn);

    for (int p = 0; p < NSTEPSn; p++) {
        const float* src = (p == 0) ? x0 : xb;

        rmsnorm3_kernel<<<Tn, 256, 0, stream>>>(src, n1, s3a, STH);
        gemm3_kernel<EPI_NONE, false><<<gTH, blk, 0, stream>>>(
            s3a, STH, W3q, SW1, Hn, qb, nullptr, 0, nullptr, Hn, Hn);
        if (p == 0) {
            gemm3_kernel<EPI_NONE, false><<<gTH, blk, 0, stream>>>(
                s3a, STH, W3k, SW1, Hn, K0, nullptr, 0, nullptr, Hn, Hn);
            gemm3_kernel<EPI_NONE, false><<<gTH, blk, 0, stream>>>(
                s3a, STH, W3v, SW1, Hn, V0, nullptr, 0, nullptr, Hn, Hn);
        }
        attn_kernel<<<(Tn * NHn) / 4, 256, 0, stream>>>(qb, K0, V0, EK, EV, toks,
                                                        tab, s3a, STH, p);
        // h2 = ctx @ Wo + src  (in-place into xb when src == xb)
        gemm3_kernel<EPI_ADD, false><<<gTH, blk, 0, stream>>>(
            s3a, STH, W3o, SW1, Hn, xb, nullptr, 0, src, Hn, Hn);
        rmsnorm3_kernel<<<Tn, 256, 0, stream>>>(xb, n2, s3a, STH);
        // Gated MLP, chunked over I (4 x 1024), pre-split weights; acc into qb.
        for (int c = 0; c < 4; c++) {
            gemm3_kernel<EPI_SILU, false><<<gTH, blk, 0, stream>>>(
                s3a, STH, W3g + (size_t)c * M1, SW4, Hn,
                Gc, nullptr, 0, nullptr, Hn, 1024);
            gemm3_kernel<EPI_MUL, true><<<gTH, blk, 0, stream>>>(
                s3a, STH, W3u + (size_t)c * M1, SW4, Hn,
                nullptr, s3g, STH, Gc, Hn, 1024);
            if (c < 3) {
                gemm3_kernel<EPI_ADD, false><<<gTH, blk, 0, stream>>>(
                    s3g, STH, W3d + (size_t)c * 1024, SW4, In,
                    qb, nullptr, 0, (c == 0) ? xb : qb, Hn, Hn);
            } else {
                gemm3_kernel<EPI_ADD, true><<<gTH, blk, 0, stream>>>(
                    s3g, STH, W3d + (size_t)c * 1024, SW4, In,
                    nullptr, s3a, STH, qb, Hn, Hn);
            }
        }
        // logits = out @ Wout + bout  (into qb)
        gemm3_kernel<EPI_BIAS, false><<<gTH, blk, 0, stream>>>(
            s3a, STH, W3t, SW1, Hn, qb, nullptr, 0, bout, Hn, Vn);
        argmax_kernel<<<Tn, 256, 0, stream>>>(qb, toks, p);
        if (p < NSTEPSn - 1) embed_kernel<<<Tn, 256, 0, stream>>>(Emb, toks, xb, p);
    }
}

// Round 8
// 7468.847 us; speedup vs baseline: 3.6198x; 1.0409x over previous
//
#include <hip/hip_runtime.h>
#include <cmath>

#define Tn 4096
#define Hn 1024
#define NHn 16
#define HDn 64
#define In 4096
#define Vn 1024
#define NSTEPSn 8

enum { EPI_NONE = 0, EPI_ADD = 1, EPI_SILU = 2, EPI_MUL = 3, EPI_BIAS = 4 };

typedef __attribute__((ext_vector_type(8))) short bf16x8;
typedef __attribute__((ext_vector_type(4))) float f32x4;

__device__ inline unsigned short bf16rne(float x) {
    unsigned int u = __float_as_uint(x);
    u += 0x7fff + ((u >> 16) & 1);
    return (unsigned short)(u >> 16);
}
__device__ inline float bf2f(unsigned short h) {
    return __uint_as_float(((unsigned int)h) << 16);
}
__device__ inline void split3(float x, unsigned short& h, unsigned short& m,
                              unsigned short& l) {
    h = bf16rne(x);
    float r = x - bf2f(h);
    m = bf16rne(r);
    float r2 = r - bf2f(m);
    l = bf16rne(r2);
}

// Async global->LDS, 16B per lane (wave-uniform LDS base; HW scatters lane*16).
__device__ __forceinline__ void gload_lds(const unsigned short* g,
                                          const unsigned short* l) {
    __builtin_amdgcn_global_load_lds(
        (const __attribute__((address_space(1))) unsigned int*)(uintptr_t)g,
        (__attribute__((address_space(3))) unsigned int*)(unsigned int)(uintptr_t)l,
        16, 0, 0);
}

// ---------------- RoPE cos/sin table ----------------
__global__ void rope_tab_kernel(double2* __restrict__ tab) {
    int tid = threadIdx.x;  // 256 threads
    int j = tid >> 5, i = tid & 31;
    double inv = exp(-((double)(2 * i) * (1.0 / (double)HDn)) * 9.210340371976184);
    double ang = (double)j * inv;
    double2 cs;
    cs.x = cos(ang);
    cs.y = sin(ang);
    tab[tid] = cs;
}

// ---------------- Weight pre-split: W[K][N] fp32 -> W3[3][N][K] bf16 ----------------
__global__ __launch_bounds__(256) void presplit_kernel(const float* __restrict__ W,
                                                       unsigned short* __restrict__ W3,
                                                       int K, int N) {
    __shared__ float S[64][65];
    int k0 = blockIdx.y * 64, n0 = blockIdx.x * 64;
    int tid = threadIdx.x;
#pragma unroll
    for (int r = 0; r < 4; r++) {
        int idx = tid + r * 256;
        int kr = idx >> 4, c4 = (idx & 15) << 2;
        float4 v = *(const float4*)(W + (size_t)(k0 + kr) * N + n0 + c4);
        S[kr][c4] = v.x;
        S[kr][c4 + 1] = v.y;
        S[kr][c4 + 2] = v.z;
        S[kr][c4 + 3] = v.w;
    }
    __syncthreads();
    size_t PS = (size_t)N * K;
#pragma unroll
    for (int r = 0; r < 4; r++) {
        int idx = tid + r * 256;
        int kq = idx & 15, n = idx >> 4;
        ushort4 hq, mq, lq;
        split3(S[4 * kq + 0][n], hq.x, mq.x, lq.x);
        split3(S[4 * kq + 1][n], hq.y, mq.y, lq.y);
        split3(S[4 * kq + 2][n], hq.z, mq.z, lq.z);
        split3(S[4 * kq + 3][n], hq.w, mq.w, lq.w);
        size_t off = (size_t)(n0 + n) * K + k0 + 4 * kq;
        *(ushort4*)(W3 + off) = hq;
        *(ushort4*)(W3 + PS + off) = mq;
        *(ushort4*)(W3 + 2 * PS + off) = lq;
    }
}

// ---------------- RMSNorm -> bf16 triple planes (f64 math) ----------------
__global__ __launch_bounds__(256) void rmsnorm3_kernel(const float* __restrict__ x,
                                                       const float* __restrict__ w,
                                                       unsigned short* __restrict__ y3,
                                                       size_t stride) {
    int t = blockIdx.x;
    const float4* xr = (const float4*)(x + (size_t)t * Hn);
    float4 v = xr[threadIdx.x];
    double ss = (double)v.x * v.x + (double)v.y * v.y + (double)v.z * v.z + (double)v.w * v.w;
#pragma unroll
    for (int o = 1; o < 64; o <<= 1) ss += __shfl_xor(ss, o, 64);
    __shared__ double red[4];
    if ((threadIdx.x & 63) == 0) red[threadIdx.x >> 6] = ss;
    __syncthreads();
    double tot = red[0] + red[1] + red[2] + red[3];
    double rs = 1.0 / sqrt(tot * (1.0 / Hn) + 1e-6);
    const float4* wr = (const float4*)w;
    float4 wv = wr[threadIdx.x];
    float o[4];
    o[0] = (float)((double)v.x * rs * (double)wv.x);
    o[1] = (float)((double)v.y * rs * (double)wv.y);
    o[2] = (float)((double)v.z * rs * (double)wv.z);
    o[3] = (float)((double)v.w * rs * (double)wv.w);
    ushort4 hq, mq, lq;
    split3(o[0], hq.x, mq.x, lq.x);
    split3(o[1], hq.y, mq.y, lq.y);
    split3(o[2], hq.z, mq.z, lq.z);
    split3(o[3], hq.w, mq.w, lq.w);
    size_t off = (size_t)t * Hn + threadIdx.x * 4;
    *(ushort4*)(y3 + off) = hq;
    *(ushort4*)(y3 + stride + off) = mq;
    *(ushort4*)(y3 + 2 * stride + off) = lq;
}

// ---------------- Attention (f64 dot, table RoPE, f32 exp), out bf16 triple ----
__global__ __launch_bounds__(256) void attn_kernel(const float* __restrict__ q,
                                                   const float* __restrict__ K0,
                                                   const float* __restrict__ V0,
                                                   const float* __restrict__ EK,
                                                   const float* __restrict__ EV,
                                                   const int* __restrict__ toks,
                                                   const double2* __restrict__ tab,
                                                   unsigned short* __restrict__ ctx3,
                                                   size_t stride, int p) {
    int wave = blockIdx.x * 4 + (threadIdx.x >> 6);  // t*NH + head
    int lane = threadIdx.x & 63;
    int t = wave >> 4;
    int col = ((wave & 15) << 6) | lane;
    int i = lane & 31;
    int half = lane >> 5;
    size_t base = (size_t)wave * HDn + lane;

    double2 csp = tab[p * 32 + i];
    double qv = (double)q[base];
    double qpart = __shfl_xor(qv, 32, 64);
    double qr = half ? (qv * csp.x + qpart * csp.y) : (qv * csp.x - qpart * csp.y);

    double sc[NSTEPSn];
    int tk[NSTEPSn];
    double m = -1e300;
    for (int j = 0; j <= p; j++) {
        double kr;
        if (j == 0) {
            kr = (double)K0[base];
            tk[0] = 0;
        } else {
            int tok = toks[(size_t)t * NSTEPSn + (j - 1)];
            tk[j] = tok;
            double kv = (double)EK[(size_t)tok * Hn + col];
            double kpart = __shfl_xor(kv, 32, 64);
            double2 cs = tab[j * 32 + i];
            kr = half ? (kv * cs.x + kpart * cs.y) : (kv * cs.x - kpart * cs.y);
        }
        double pr = qr * kr;
#pragma unroll
        for (int o = 1; o < 64; o <<= 1) pr += __shfl_xor(pr, o, 64);
        sc[j] = pr * 0.125;
        m = fmax(m, sc[j]);
    }
    double den = 0.0;
    for (int j = 0; j <= p; j++) {
        sc[j] = (double)expf((float)(sc[j] - m));
        den += sc[j];
    }
    double invd = 1.0 / den;
    double acc = 0.0;
    for (int j = 0; j <= p; j++) {
        double vv = (j == 0) ? (double)V0[base] : (double)EV[(size_t)tk[j] * Hn + col];
        acc += sc[j] * vv;
    }
    unsigned short h, mm, l;
    split3((float)(acc * invd), h, mm, l);
    ctx3[base] = h;
    ctx3[stride + base] = mm;
    ctx3[2 * stride + base] = l;
}

// ---------------- bf16x3 MFMA GEMM, async LDS dbuf, XCD-swizzled grid --------
// C(M x N) = A(M x K) @ B(K x N). A planes [3][M][K], B planes [3][N][K].
// 1D grid, N-blocks fixed at 16 (N=1024). Swizzle: xcd=f&7 owns GM/8
// consecutive bm groups -> A-tile stays L2-resident per XCD.
// Block 128x64, 4 waves (2x2). Promote fp32->f64 every 2 chunks, scheduled
// right after the async prefetch issue (overlaps DMA latency).
#define ABUF 12288  // 3*128*32 ushorts
#define BBUF 6144   // 3*64*32 ushorts
template <int EPI, bool TRIPLE>
__global__ __launch_bounds__(256, 2) void gemm3_kernel(
    const unsigned short* __restrict__ A3, size_t strideA,
    const unsigned short* __restrict__ B3, size_t strideB, int ldbk,
    float* Cf, unsigned short* C3, size_t strideC,
    const float* aux, int K, int ldc) {
    __shared__ unsigned short lds[2][ABUF + BBUF];  // 72 KB

    int tid = threadIdx.x;
    int wv = tid >> 6, lane = tid & 63;
    int wr = wv >> 1, wc = wv & 1;

    // ---- XCD swizzle: f -> (bm, bn); GN = 16 fixed ----
    int f = blockIdx.x;
    int bmPer = gridDim.x >> 7;          // GM/8  (512->4, 128->1)
    int xcd = f & 7;
    int j = f >> 3;
    int mblk = (xcd * bmPer + (j >> 4)) * 128;
    int nblk = (j & 15) * 64;

    // ---- per-wave staging segments: 9 x 1KB (A: 24 segs, B: 12 segs) ----
    int lrow = lane >> 2, lcol = (lane & 3) << 3;
    const unsigned short* gseg0;
    const unsigned short* gseg1;
    const unsigned short* gseg2;
    const unsigned short* gseg3;
    const unsigned short* gseg4;
    const unsigned short* gseg5;
    const unsigned short* gseg6;
    const unsigned short* gseg7;
    const unsigned short* gseg8;
    unsigned lseg0, lseg1, lseg2, lseg3, lseg4, lseg5, lseg6, lseg7, lseg8;
#define SEGINIT(IDX)                                                              \
    {                                                                             \
        int s = wv * 9 + IDX;                                                     \
        if (s < 24) {                                                             \
            int pl = s >> 3, sub = s & 7;                                         \
            gseg##IDX = A3 + (size_t)pl * strideA +                               \
                        (size_t)(mblk + sub * 16 + lrow) * K + lcol;              \
            lseg##IDX = pl * 4096 + sub * 512;                                    \
        } else {                                                                  \
            int u = s - 24;                                                       \
            int pl = u >> 2, sub = u & 3;                                         \
            gseg##IDX = B3 + (size_t)pl * strideB +                               \
                        (size_t)(nblk + sub * 16 + lrow) * ldbk + lcol;           \
            lseg##IDX = ABUF + pl * 2048 + sub * 512;                             \
        }                                                                         \
    }
    SEGINIT(0) SEGINIT(1) SEGINIT(2) SEGINIT(3) SEGINIT(4)
    SEGINIT(5) SEGINIT(6) SEGINIT(7) SEGINIT(8)
#undef SEGINIT

#define ISSUE(BUF, KOFF)                                                          \
    {                                                                             \
        unsigned short* lb = &lds[BUF][0];                                        \
        gload_lds(gseg0 + (KOFF), lb + lseg0);                                    \
        gload_lds(gseg1 + (KOFF), lb + lseg1);                                    \
        gload_lds(gseg2 + (KOFF), lb + lseg2);                                    \
        gload_lds(gseg3 + (KOFF), lb + lseg3);                                    \
        gload_lds(gseg4 + (KOFF), lb + lseg4);                                    \
        gload_lds(gseg5 + (KOFF), lb + lseg5);                                    \
        gload_lds(gseg6 + (KOFF), lb + lseg6);                                    \
        gload_lds(gseg7 + (KOFF), lb + lseg7);                                    \
        gload_lds(gseg8 + (KOFF), lb + lseg8);                                    \
    }

    f32x4 acc[4][2];
    double accd[4][2][4];
#pragma unroll
    for (int mt = 0; mt < 4; mt++)
#pragma unroll
        for (int nt = 0; nt < 2; nt++) {
            acc[mt][nt] = (f32x4){0.f, 0.f, 0.f, 0.f};
#pragma unroll
            for (int r = 0; r < 4; r++) accd[mt][nt][r] = 0.0;
        }

    int rA = lane & 15;
    int kq = (lane >> 4) << 3;

    int nc = K >> 5;
    ISSUE(0, 0)
    __syncthreads();
    for (int c = 0; c < nc; ++c) {
        int cur = c & 1;
        if (c + 1 < nc) ISSUE(cur ^ 1, (c + 1) << 5)

        // promote the two *completed* chunks while the DMA is in flight
        if (c > 0 && (c & 1) == 0) {
#pragma unroll
            for (int mt = 0; mt < 4; mt++)
#pragma unroll
                for (int nt = 0; nt < 2; nt++)
#pragma unroll
                    for (int r = 0; r < 4; r++) {
                        accd[mt][nt][r] += (double)acc[mt][nt][r];
                        acc[mt][nt][r] = 0.f;
                    }
        }

        const unsigned short* base = &lds[cur][0];
        bf16x8 Af[3][4], Bf[3][2];
#pragma unroll
        for (int pl = 0; pl < 3; pl++) {
#pragma unroll
            for (int mt = 0; mt < 4; mt++)
                Af[pl][mt] = *(const bf16x8*)(base + pl * 4096 +
                                              (wr * 64 + mt * 16 + rA) * 32 + kq);
#pragma unroll
            for (int nt = 0; nt < 2; nt++)
                Bf[pl][nt] = *(const bf16x8*)(base + ABUF + pl * 2048 +
                                              (wc * 32 + nt * 16 + rA) * 32 + kq);
        }
#pragma unroll
        for (int mt = 0; mt < 4; mt++)
#pragma unroll
            for (int nt = 0; nt < 2; nt++) {
                f32x4 a = acc[mt][nt];
                a = __builtin_amdgcn_mfma_f32_16x16x32_bf16(Af[0][mt], Bf[0][nt], a, 0, 0, 0);
                a = __builtin_amdgcn_mfma_f32_16x16x32_bf16(Af[0][mt], Bf[1][nt], a, 0, 0, 0);
                a = __builtin_amdgcn_mfma_f32_16x16x32_bf16(Af[1][mt], Bf[0][nt], a, 0, 0, 0);
                a = __builtin_amdgcn_mfma_f32_16x16x32_bf16(Af[1][mt], Bf[1][nt], a, 0, 0, 0);
                a = __builtin_amdgcn_mfma_f32_16x16x32_bf16(Af[0][mt], Bf[2][nt], a, 0, 0, 0);
                a = __builtin_amdgcn_mfma_f32_16x16x32_bf16(Af[2][mt], Bf[0][nt], a, 0, 0, 0);
                acc[mt][nt] = a;
            }
        __syncthreads();  // drains prefetch + guards buffer reuse
    }
#undef ISSUE

    // final promote (last 2 chunks)
#pragma unroll
    for (int mt = 0; mt < 4; mt++)
#pragma unroll
        for (int nt = 0; nt < 2; nt++)
#pragma unroll
            for (int r = 0; r < 4; r++) accd[mt][nt][r] += (double)acc[mt][nt][r];

    // ---- epilogue (f64), write f32 or bf16-triple ----
#pragma unroll
    for (int mt = 0; mt < 4; mt++)
#pragma unroll
        for (int nt = 0; nt < 2; nt++) {
            int n = nblk + wc * 32 + nt * 16 + (lane & 15);
            int mb = mblk + wr * 64 + mt * 16 + ((lane >> 4) << 2);
#pragma unroll
            for (int r = 0; r < 4; r++) {
                int m = mb + r;
                size_t off = (size_t)m * ldc + n;
                double v = accd[mt][nt][r];
                if (EPI == EPI_ADD) v += (double)aux[off];
                if (EPI == EPI_SILU) {
                    float vf = (float)v;
                    v = (double)(vf / (1.0f + expf(-vf)));
                }
                if (EPI == EPI_MUL) v *= (double)aux[off];
                if (EPI == EPI_BIAS) v += (double)aux[n];
                if (TRIPLE) {
                    unsigned short h, mm, l;
                    split3((float)v, h, mm, l);
                    C3[off] = h;
                    C3[strideC + off] = mm;
                    C3[2 * strideC + off] = l;
                } else {
                    Cf[off] = (float)v;
                }
            }
        }
}

// ---------------- Argmax over f32 logits (first-max tie-break) ----------------
__global__ __launch_bounds__(256) void argmax_kernel(const float* __restrict__ logits,
                                                     int* __restrict__ out_tok, int p) {
    int t = blockIdx.x;
    const float* lr = logits + (size_t)t * Vn;
    float bv = -INFINITY;
    int bi = 0x7fffffff;
    for (int j = threadIdx.x; j < Vn; j += 256) {
        float v = lr[j];
        if (v > bv || (v == bv && j < bi)) {
            bv = v;
            bi = j;
        }
    }
#pragma unroll
    for (int o = 1; o < 64; o <<= 1) {
        float ov = __shfl_xor(bv, o, 64);
        int oi = __shfl_xor(bi, o, 64);
        if (ov > bv || (ov == bv && oi < bi)) {
            bv = ov;
            bi = oi;
        }
    }
    __shared__ float sv[4];
    __shared__ int si[4];
    if ((threadIdx.x & 63) == 0) {
        sv[threadIdx.x >> 6] = bv;
        si[threadIdx.x >> 6] = bi;
    }
    __syncthreads();
    if (threadIdx.x == 0) {
        for (int w = 1; w < 4; w++) {
            if (sv[w] > bv || (sv[w] == bv && si[w] < bi)) {
                bv = sv[w];
                bi = si[w];
            }
        }
        out_tok[(size_t)t * NSTEPSn + p] = bi;
    }
}

// ---------------- Embedding gather ----------------
__global__ __launch_bounds__(256) void embed_kernel(const float* __restrict__ E,
                                                    const int* __restrict__ toks,
                                                    float* __restrict__ x, int p) {
    int t = blockIdx.x;
    int tok = toks[(size_t)t * NSTEPSn + p];
    float4 v = ((const float4*)(E + (size_t)tok * Hn))[threadIdx.x];
    ((float4*)(x + (size_t)t * Hn))[threadIdx.x] = v;
}

extern "C" void kernel_launch(void* const* d_in, const int* in_sizes, int n_in,
                              void* d_out, int out_size, void* d_ws, size_t ws_size,
                              hipStream_t stream) {
    const float* x0 = (const float*)d_in[0];
    const float* Wq = (const float*)d_in[1];
    const float* Wk = (const float*)d_in[2];
    const float* Wv = (const float*)d_in[3];
    const float* Wo = (const float*)d_in[4];
    const float* Wg = (const float*)d_in[5];
    const float* Wu = (const float*)d_in[6];
    const float* Wd = (const float*)d_in[7];
    const float* n1 = (const float*)d_in[8];
    const float* n2 = (const float*)d_in[9];
    const float* Emb = (const float*)d_in[10];
    const float* Wout = (const float*)d_in[11];
    const float* bout = (const float*)d_in[12];
    int* toks = (int*)d_out;

    float* ws = (float*)d_ws;
    const size_t M1 = 1024 * 1024;
    float* EK = ws;                  // V x H fp32           4MB
    float* EV = ws + 1 * M1;         //                      4MB
    float* K0 = ws + 2 * M1;         // T x H fp32           16MB
    float* V0 = ws + 6 * M1;         //                      16MB
    float* xb = ws + 10 * M1;        // residual hidden      16MB
    float* qb = ws + 14 * M1;        // q / MLP acc / logits 16MB
    float* Gc = ws + 18 * M1;        // silu chunk fp32      16MB
    unsigned short* s3a = (unsigned short*)(ws + 22 * M1);  // triple TxH  24MB
    unsigned short* s3g = (unsigned short*)(ws + 28 * M1);  // triple TxH  24MB
    double2* tab = (double2*)(ws + 34 * M1);                // 256 double2  4KB
    unsigned short* W3q = (unsigned short*)(ws + 34 * M1 + 1024);  // 6MB
    unsigned short* W3k = W3q + 3 * M1;                            // 6MB
    unsigned short* W3v = W3k + 3 * M1;                            // 6MB
    unsigned short* W3o = W3v + 3 * M1;                            // 6MB
    unsigned short* W3t = W3o + 3 * M1;  // Wout                     6MB
    unsigned short* W3g = W3t + 3 * M1;                            // 24MB
    unsigned short* W3u = W3g + 12 * M1;                           // 24MB
    unsigned short* W3d = W3u + 12 * M1;                           // 24MB
    // total ~= 238 MB

    const size_t STH = (size_t)Tn * Hn;  // plane stride, T x 1024 triples
    const size_t SVH = (size_t)Vn * Hn;  // plane stride, V x H triple
    const size_t SW1 = M1;               // plane stride, 1M-element weights
    const size_t SW4 = 4 * M1;           // plane stride, 4M-element weights

    dim3 blk(256);
    const int gTH = 512;  // (M/128=32) x (N/64=16), 1D swizzled
    const int gVH = 128;  // (M/128=8)  x 16

    // ---- One-time precompute ----
    rope_tab_kernel<<<1, 256, 0, stream>>>(tab);
    presplit_kernel<<<dim3(16, 16), blk, 0, stream>>>(Wq, W3q, Hn, Hn);
    presplit_kernel<<<dim3(16, 16), blk, 0, stream>>>(Wk, W3k, Hn, Hn);
    presplit_kernel<<<dim3(16, 16), blk, 0, stream>>>(Wv, W3v, Hn, Hn);
    presplit_kernel<<<dim3(16, 16), blk, 0, stream>>>(Wo, W3o, Hn, Hn);
    presplit_kernel<<<dim3(16, 16), blk, 0, stream>>>(Wout, W3t, Hn, Vn);
    presplit_kernel<<<dim3(In / 64, Hn / 64), blk, 0, stream>>>(Wg, W3g, Hn, In);
    presplit_kernel<<<dim3(In / 64, Hn / 64), blk, 0, stream>>>(Wu, W3u, Hn, In);
    presplit_kernel<<<dim3(Hn / 64, In / 64), blk, 0, stream>>>(Wd, W3d, In, Hn);
    rmsnorm3_kernel<<<Vn, 256, 0, stream>>>(Emb, n1, s3a, SVH);
    gemm3_kernel<EPI_NONE, false><<<gVH, blk, 0, stream>>>(
        s3a, SVH, W3k, SW1, Hn, EK, nullptr, 0, nullptr, Hn, Hn);
    gemm3_kernel<EPI_NONE, false><<<gVH, blk, 0, stream>>>(
        s3a, SVH, W3v, SW1, Hn, EV, nullptr, 0, nullptr, Hn, Hn);

    for (int p = 0; p < NSTEPSn; p++) {
        const float* src = (p == 0) ? x0 : xb;

        rmsnorm3_kernel<<<Tn, 256, 0, stream>>>(src, n1, s3a, STH);
        gemm3_kernel<EPI_NONE, false><<<gTH, blk, 0, stream>>>(
            s3a, STH, W3q, SW1, Hn, qb, nullptr, 0, nullptr, Hn, Hn);
        if (p == 0) {
            gemm3_kernel<EPI_NONE, false><<<gTH, blk, 0, stream>>>(
                s3a, STH, W3k, SW1, Hn, K0, nullptr, 0, nullptr, Hn, Hn);
            gemm3_kernel<EPI_NONE, false><<<gTH, blk, 0, stream>>>(
                s3a, STH, W3v, SW1, Hn, V0, nullptr, 0, nullptr, Hn, Hn);
        }
        attn_kernel<<<(Tn * NHn) / 4, 256, 0, stream>>>(qb, K0, V0, EK, EV, toks,
                                                        tab, s3a, STH, p);
        // h2 = ctx @ Wo + src  (in-place into xb when src == xb)
        gemm3_kernel<EPI_ADD, false><<<gTH, blk, 0, stream>>>(
            s3a, STH, W3o, SW1, Hn, xb, nullptr, 0, src, Hn, Hn);
        rmsnorm3_kernel<<<Tn, 256, 0, stream>>>(xb, n2, s3a, STH);
        // Gated MLP, chunked over I (4 x 1024), pre-split weights; acc into qb.
        for (int c = 0; c < 4; c++) {
            gemm3_kernel<EPI_SILU, false><<<gTH, blk, 0, stream>>>(
                s3a, STH, W3g + (size_t)c * M1, SW4, Hn,
                Gc, nullptr, 0, nullptr, Hn, 1024);
            gemm3_kernel<EPI_MUL, true><<<gTH, blk, 0, stream>>>(
                s3a, STH, W3u + (size_t)c * M1, SW4, Hn,
                nullptr, s3g, STH, Gc, Hn, 1024);
            if (c < 3) {
                gemm3_kernel<EPI_ADD, false><<<gTH, blk, 0, stream>>>(
                    s3g, STH, W3d + (size_t)c * 1024, SW4, In,
                    qb, nullptr, 0, (c == 0) ? xb : qb, Hn, Hn);
            } else {
                gemm3_kernel<EPI_ADD, true><<<gTH, blk, 0, stream>>>(
                    s3g, STH, W3d + (size_t)c * 1024, SW4, In,
                    nullptr, s3a, STH, qb, Hn, Hn);
            }
        }
        // logits = out @ Wout + bout  (into qb)
        gemm3_kernel<EPI_BIAS, false><<<gTH, blk, 0, stream>>>(
            s3a, STH, W3t, SW1, Hn, qb, nullptr, 0, bout, Hn, Vn);
        argmax_kernel<<<Tn, 256, 0, stream>>>(qb, toks, p);
        if (p < NSTEPSn - 1) embed_kernel<<<Tn, 256, 0, stream>>>(Emb, toks, xb, p);
    }
}